// Round 12
// baseline (153.165 us; speedup 1.0000x reference)
//
#include <hip/hip_runtime.h>
#include <hip/hip_bf16.h>

typedef __hip_bfloat16 bf16;
typedef __attribute__((ext_vector_type(8))) short bf16x8;
typedef __attribute__((ext_vector_type(4))) float f32x4;

#define NBATCH 16
#define CCH    512
#define PP     1024
#define OCH    64

__device__ __forceinline__ void gload16(const void* g, void* l) {
  __builtin_amdgcn_global_load_lds(
      (const __attribute__((address_space(1))) void*)g,
      (__attribute__((address_space(3))) void*)l, 16, 0, 0);
}
__device__ __forceinline__ float bf2f(bf16 v) { return __bfloat162float(v); }
__device__ __forceinline__ bf16  f2bf(float v) { return __float2bfloat16(v); }

__device__ __forceinline__ void barrier_vm0() {
  asm volatile("s_waitcnt vmcnt(0)" ::: "memory");
  __builtin_amdgcn_s_barrier();
  asm volatile("" ::: "memory");
}
__device__ __forceinline__ void barrier_lgkm0() {
  asm volatile("s_waitcnt lgkmcnt(0)" ::: "memory");
  __builtin_amdgcn_s_barrier();
  asm volatile("" ::: "memory");
}
__device__ __forceinline__ void barrier_plain() {
  asm volatile("" ::: "memory");
  __builtin_amdgcn_s_barrier();
  asm volatile("" ::: "memory");
}

// --------------------------------------- merged prep (weights) + transpose/split
__global__ __launch_bounds__(256) void prep_transpose_kernel(
    const float* __restrict__ x,
    const float* __restrict__ key_w, const float* __restrict__ key_b,
    const float* __restrict__ query_w, const float* __restrict__ query_b,
    const float* __restrict__ value_w, const float* __restrict__ value_b,
    bf16* __restrict__ xhi, bf16* __restrict__ xlo,
    bf16* __restrict__ wqk_hi, bf16* __restrict__ wqk_lo,
    bf16* __restrict__ wv, float* __restrict__ bias_qk, float* __restrict__ bias_v) {
  __shared__ float tile[64 * 65];
  const int bid = blockIdx.x;
  const int tid = threadIdx.x;
  if (bid < 2048) {
    const int pt = bid & 15, ct = (bid >> 4) & 7, n = bid >> 7;
    const size_t xbase = ((size_t)n * CCH + ct * 64) * PP + pt * 64;
#pragma unroll
    for (int i = 0; i < 4; ++i) {
      const int chunk = i * 256 + tid;
      const int row = chunk >> 4, c4 = chunk & 15;
      const f32x4 v = *(const f32x4*)&x[xbase + (size_t)row * PP + c4 * 4];
#pragma unroll
      for (int m = 0; m < 4; ++m) tile[row * 65 + c4 * 4 + m] = v[m];
    }
    __syncthreads();
    const size_t obase = ((size_t)n * PP + pt * 64) * CCH + ct * 64;
#pragma unroll
    for (int ii = 0; ii < 2; ++ii) {
      const int p = ii * 32 + (tid >> 3);
      const int cu = tid & 7;
      bf16x8 hv, lv;
#pragma unroll
      for (int j = 0; j < 8; ++j) {
        const float f = tile[(cu * 8 + j) * 65 + p];
        const bf16 h = f2bf(f);
        const bf16 lo_ = f2bf(f - bf2f(h));
        short hs, ls;
        __builtin_memcpy(&hs, &h, 2);
        __builtin_memcpy(&ls, &lo_, 2);
        hv[j] = hs;
        lv[j] = ls;
      }
      const size_t oidx = obase + (size_t)p * CCH + cu * 8;
      *(bf16x8*)&xhi[oidx] = hv;
      *(bf16x8*)&xlo[oidx] = lv;
    }
  } else {
    const int t = (bid - 2048) * 256 + tid;
    const int TOT_QK = 128 * 512;
    const int TOT_V  = 512 * 512;
    if (t < TOT_QK) {
      const int m = t >> 9, c = t & 511;
      const float v = (m < 64) ? query_w[m * 512 + c] : key_w[(m - 64) * 512 + c];
      const bf16 hi = f2bf(v);
      wqk_hi[t] = hi;
      wqk_lo[t] = f2bf(v - bf2f(hi));
    } else if (t < TOT_QK + TOT_V) {
      const int u = t - TOT_QK;
      wv[u] = f2bf(value_w[u]);
    } else if (t < TOT_QK + TOT_V + 128) {
      const int m = t - (TOT_QK + TOT_V);
      bias_qk[m] = (m < 64) ? query_b[m] : key_b[m - 64];
    } else if (t < TOT_QK + TOT_V + 128 + 512) {
      const int m = t - (TOT_QK + TOT_V + 128);
      bias_v[m] = value_b[m];
    }
  }
}

// ------------------------------------- merged Q/K projection + V projection GEMM
__global__ __launch_bounds__(256) void gemm_qkv_kernel(
    const bf16* __restrict__ Whi, const bf16* __restrict__ Wlo,
    const bf16* __restrict__ Wv,
    const bf16* __restrict__ XThi, const bf16* __restrict__ XTlo,
    const float* __restrict__ biasqk, const float* __restrict__ biasv,
    bf16* __restrict__ qhi, bf16* __restrict__ qlo,
    bf16* __restrict__ khi, bf16* __restrict__ klo,
    bf16* __restrict__ Vout) {
  __shared__ __align__(16) bf16 sm[4 * 128 * 64];  // 64KB union
  const int tid = threadIdx.x, l = tid & 63, w = tid >> 6;
  const int lrow = l >> 3, lcol = (l & 7) * 8, wr = w >> 1, wc = w & 1;
  const f32x4 z = {0.f, 0.f, 0.f, 0.f};
  f32x4 acc[4][4];
#pragma unroll
  for (int i = 0; i < 4; ++i)
#pragma unroll
    for (int j = 0; j < 4; ++j) acc[i][j] = z;

  if (blockIdx.x < 128) {
    // ---------------- qk path
    const int id = blockIdx.x;
    const int n0 = (id & 7) * 128, bn = id >> 3;
    const size_t xoff = (size_t)bn * PP * CCH;
    bf16* Ash = sm;
    bf16* Asl = sm + 8192;
    bf16* Bsh = sm + 16384;
    bf16* Bsl = sm + 24576;
    for (int kt = 0; kt < CCH; kt += 64) {
#pragma unroll
      for (int it = 0; it < 4; ++it) {
        const int chunk = w * 4 + it;
        const int ar = chunk * 8 + lrow;
        const int br = n0 + chunk * 8 + lrow;
        gload16(Whi + (size_t)ar * CCH + kt + lcol, &Ash[chunk * 512]);
        gload16(Wlo + (size_t)ar * CCH + kt + lcol, &Asl[chunk * 512]);
        gload16(XThi + xoff + (size_t)br * CCH + kt + lcol, &Bsh[chunk * 512]);
        gload16(XTlo + xoff + (size_t)br * CCH + kt + lcol, &Bsl[chunk * 512]);
      }
      __syncthreads();
#pragma unroll
      for (int kk = 0; kk < 2; ++kk) {
        bf16x8 ah[4], al[4], bh[4], bl[4];
        const int ko = kk * 32 + (l >> 4) * 8;
#pragma unroll
        for (int i = 0; i < 4; ++i) {
          const int r = (wr * 64 + i * 16 + (l & 15)) * 64 + ko;
          ah[i] = *(const bf16x8*)&Ash[r];
          al[i] = *(const bf16x8*)&Asl[r];
        }
#pragma unroll
        for (int j = 0; j < 4; ++j) {
          const int r = (wc * 64 + j * 16 + (l & 15)) * 64 + ko;
          bh[j] = *(const bf16x8*)&Bsh[r];
          bl[j] = *(const bf16x8*)&Bsl[r];
        }
#pragma unroll
        for (int i = 0; i < 4; ++i)
#pragma unroll
          for (int j = 0; j < 4; ++j) {
            acc[i][j] = __builtin_amdgcn_mfma_f32_16x16x32_bf16(ah[i], bh[j], acc[i][j], 0, 0, 0);
            acc[i][j] = __builtin_amdgcn_mfma_f32_16x16x32_bf16(ah[i], bl[j], acc[i][j], 0, 0, 0);
            acc[i][j] = __builtin_amdgcn_mfma_f32_16x16x32_bf16(al[i], bh[j], acc[i][j], 0, 0, 0);
          }
      }
      __syncthreads();
    }
    const size_t qoff = (size_t)bn * PP * OCH;
#pragma unroll
    for (int i = 0; i < 4; ++i)
#pragma unroll
      for (int j = 0; j < 4; ++j)
#pragma unroll
        for (int r = 0; r < 4; ++r) {
          const int m = wr * 64 + i * 16 + (l >> 4) * 4 + r;
          const int p = n0 + wc * 64 + j * 16 + (l & 15);
          const float v = acc[i][j][r] + biasqk[m];
          const bf16 hi = f2bf(v);
          const bf16 lo = f2bf(v - bf2f(hi));
          if (m < 64) {
            qhi[qoff + (size_t)p * OCH + m] = hi;
            qlo[qoff + (size_t)p * OCH + m] = lo;
          } else {
            khi[qoff + (size_t)p * OCH + (m - 64)] = hi;
            klo[qoff + (size_t)p * OCH + (m - 64)] = lo;
          }
        }
  } else {
    // ---------------- v path
    const int id = blockIdx.x - 128;
    const int n0 = (id & 7) * 128, m0 = ((id >> 3) & 3) * 128, bn = id >> 5;
    const size_t xoff = (size_t)bn * PP * CCH;
    bf16* As = sm;
    bf16* Bs = sm + 8192;
    for (int kt = 0; kt < CCH; kt += 64) {
#pragma unroll
      for (int it = 0; it < 4; ++it) {
        const int chunk = w * 4 + it;
        gload16(Wv + (size_t)(m0 + chunk * 8 + lrow) * CCH + kt + lcol, &As[chunk * 512]);
        gload16(XThi + xoff + (size_t)(n0 + chunk * 8 + lrow) * CCH + kt + lcol, &Bs[chunk * 512]);
      }
      __syncthreads();
#pragma unroll
      for (int kk = 0; kk < 2; ++kk) {
        bf16x8 a[4], b[4];
        const int ko = kk * 32 + (l >> 4) * 8;
#pragma unroll
        for (int i = 0; i < 4; ++i) a[i] = *(const bf16x8*)&As[(wr * 64 + i * 16 + (l & 15)) * 64 + ko];
#pragma unroll
        for (int j = 0; j < 4; ++j) b[j] = *(const bf16x8*)&Bs[(wc * 64 + j * 16 + (l & 15)) * 64 + ko];
#pragma unroll
        for (int i = 0; i < 4; ++i)
#pragma unroll
          for (int j = 0; j < 4; ++j)
            acc[i][j] = __builtin_amdgcn_mfma_f32_16x16x32_bf16(a[i], b[j], acc[i][j], 0, 0, 0);
      }
      __syncthreads();
    }
#pragma unroll
    for (int i = 0; i < 4; ++i)
#pragma unroll
      for (int j = 0; j < 4; ++j)
#pragma unroll
        for (int r = 0; r < 4; ++r) {
          const int m = m0 + wr * 64 + i * 16 + (l >> 4) * 4 + r;
          const int p = n0 + wc * 64 + j * 16 + (l & 15);
          Vout[(size_t)bn * CCH * PP + (size_t)m * PP + p] = f2bf(acc[i][j][r] + biasv[m]);
        }
  }
}

// ---------------------------------------------------- fused flash attention + epilogue
// R3/R7 dataflow exactly; ONE delta: V staged single-buffered (32 KB saved ->
// 68 KB loop LDS -> 2 independent blocks/CU, m114 cross-block overlap). Extra
// plain barrier per tile guards V(t) reads vs stage_v(t+1) overwrite.
#define KT 32
#define NT 32

__global__ __launch_bounds__(512, 4) void fused_attn_kernel(
    const bf16* __restrict__ qhi, const bf16* __restrict__ qlo,
    const bf16* __restrict__ khi, const bf16* __restrict__ klo,
    const bf16* __restrict__ vbuf, const float* __restrict__ tensor,
    const float* __restrict__ gamma, float* __restrict__ out) {
  // smem: Qh 0..8K, Ql 8..16K, Kh dbuf 16K..24K, Kl dbuf 24K..32K,
  // V single 32K..64K, P 64K..68K. epilogue rep[128][68] f32 aliases base.
  __shared__ __align__(16) char smem[69632];
  __shared__ float red[128];
  __shared__ float fq[64];
  const int tid = threadIdx.x, l = tid & 63, w = tid >> 6;

  // XCD-grouped decode: XCD x gets batches {2x, 2x+1}
  const int d = blockIdx.x;
  const int idx = d >> 3;
  const int bn = (d & 7) * 2 + (idx >> 4);
  const int qt0 = (idx & 15) * 64;

  const size_t qkoff = (size_t)bn * PP * OCH;
  const size_t voff  = (size_t)bn * CCH * PP;
  char* Qh = smem;
  char* Ql = smem + 8192;
  char* Vb = smem + 32768;
  char* Pb = smem + 65536;

  // ---- stage Q (hi/lo), once
  {
    const int s = (w << 6) | l;
    const int row = s >> 3, pu = s & 7, lu = pu ^ (row & 7);
    const size_t src = qkoff + (size_t)(qt0 + row) * OCH + lu * 8;
    gload16(qhi + src, Qh + w * 1024);
    gload16(qlo + src, Ql + w * 1024);
  }

  auto stage_k = [&](int t, int buf) {
    char* base = smem + 16384 + ((w >= 4) ? 8192 : 0) + buf * 4096;
    const bf16* src0 = (w < 4) ? khi : klo;
    const int s = ((w & 3) << 6) | l;
    const int row = s >> 3, pu = s & 7, lu = pu ^ (row & 7);
    gload16(src0 + qkoff + (size_t)(t * KT + row) * OCH + lu * 8,
            base + (w & 3) * 1024);
  };
  auto stage_v = [&](int t) {
#pragma unroll
    for (int c4 = 0; c4 < 4; ++c4) {
      const int s = (w << 8) + (c4 << 6) + l;
      const int row = s >> 2, pu = s & 3, lu = pu ^ ((row >> 1) & 3);
      const bf16* srcp = vbuf + voff + (size_t)row * PP + t * KT + lu * 8;
      gload16(srcp, Vb + ((w << 8) + (c4 << 6)) * 16);
    }
  };

  stage_k(0, 0);
  stage_v(0);
  barrier_vm0();  // Q + K(0) + V(0) resident

  // ---- hoist Q fragments (loop-invariant)
  bf16x8 ah[2], al[2];
  {
    const int qrow = ((w & 3) << 4) + (l & 15);
#pragma unroll
    for (int h = 0; h < 2; ++h) {
      const int lu = (l >> 4) + 4 * h, pu = lu ^ (qrow & 7);
      ah[h] = *(const bf16x8*)(Qh + qrow * 128 + pu * 16);
      al[h] = *(const bf16x8*)(Ql + qrow * 128 + pu * 16);
    }
  }

  f32x4 acc[4][4];
  const f32x4 z = {0.f, 0.f, 0.f, 0.f};
#pragma unroll
  for (int i = 0; i < 4; ++i)
#pragma unroll
    for (int j = 0; j < 4; ++j) acc[i][j] = z;
  float psum[4] = {0.f, 0.f, 0.f, 0.f};
  const int kf = w >> 2;

  for (int t = 0; t < NT; ++t) {
    const int buf = t & 1;
    if (t) barrier_vm0();  // K(t) + V(t) staged everywhere

    if (t + 1 < NT) stage_k(t + 1, buf ^ 1);

    // ---- S = Q.K^T for this wave's (qf = w&3, kf) 16x16 fragment
    char* khB = smem + 16384 + buf * 4096;
    char* klB = smem + 24576 + buf * 4096;
    bf16x8 kh_[2], kl_[2];
    const int krow = (kf << 4) + (l & 15);
#pragma unroll
    for (int h = 0; h < 2; ++h) {
      const int lu = (l >> 4) + 4 * h, pu = lu ^ (krow & 7);
      kh_[h] = *(const bf16x8*)(khB + krow * 128 + pu * 16);
      kl_[h] = *(const bf16x8*)(klB + krow * 128 + pu * 16);
    }
    __builtin_amdgcn_s_setprio(1);
    f32x4 s = z;
    s = __builtin_amdgcn_mfma_f32_16x16x32_bf16(ah[0], kh_[0], s, 0, 0, 0);
    s = __builtin_amdgcn_mfma_f32_16x16x32_bf16(ah[1], kh_[1], s, 0, 0, 0);
    s = __builtin_amdgcn_mfma_f32_16x16x32_bf16(al[0], kh_[0], s, 0, 0, 0);
    s = __builtin_amdgcn_mfma_f32_16x16x32_bf16(al[1], kh_[1], s, 0, 0, 0);
    s = __builtin_amdgcn_mfma_f32_16x16x32_bf16(ah[0], kl_[0], s, 0, 0, 0);
    s = __builtin_amdgcn_mfma_f32_16x16x32_bf16(ah[1], kl_[1], s, 0, 0, 0);
    __builtin_amdgcn_s_setprio(0);

    // ---- P = exp(s - 30) -> bf16, write to P_lds (swizzled), track row sums
#pragma unroll
    for (int r = 0; r < 4; ++r) {
      const float pv = __expf(s[r] - 30.f);
      const bf16 pb16 = f2bf(pv);
      psum[r] += bf2f(pb16);
      const int q = ((w & 3) << 4) + ((l >> 4) << 2) + r;
      const int k = (kf << 4) + (l & 15);
      const int pu = (k >> 3) ^ ((q >> 1) & 3);
      *(bf16*)(Pb + q * 64 + pu * 16 + (k & 7) * 2) = pb16;
    }
    barrier_lgkm0();  // P visible to all waves

    // ---- PV: acc[c-frag i][q-frag j] += V * P^T
    bf16x8 va[4], pb[4];
#pragma unroll
    for (int i = 0; i < 4; ++i) {
      const int crow = (w << 6) + (i << 4) + (l & 15);
      const int pu = (l >> 4) ^ ((crow >> 1) & 3);
      va[i] = *(const bf16x8*)(Vb + crow * 64 + pu * 16);
    }
#pragma unroll
    for (int j = 0; j < 4; ++j) {
      const int prow = (j << 4) + (l & 15);
      const int pu = (l >> 4) ^ ((prow >> 1) & 3);
      pb[j] = *(const bf16x8*)(Pb + prow * 64 + pu * 16);
    }
    __builtin_amdgcn_s_setprio(1);
#pragma unroll
    for (int i = 0; i < 4; ++i)
#pragma unroll
      for (int j = 0; j < 4; ++j)
        acc[i][j] = __builtin_amdgcn_mfma_f32_16x16x32_bf16(va[i], pb[j], acc[i][j], 0, 0, 0);
    __builtin_amdgcn_s_setprio(0);

    // ---- all waves consumed V(t) -> safe to overwrite; issue V(t+1)
    barrier_plain();
    if (t + 1 < NT) stage_v(t + 1);
  }

  // ---- lsum: reduce psum over the 16 lanes sharing a q-row, combine kf halves
#pragma unroll
  for (int off = 1; off < 16; off <<= 1)
#pragma unroll
    for (int r = 0; r < 4; ++r) psum[r] += __shfl_xor(psum[r], off);
  if ((l & 15) == 0) {
#pragma unroll
    for (int r = 0; r < 4; ++r) {
      const int q = ((w & 3) << 4) + ((l >> 4) << 2) + r;
      red[q * 2 + kf] = psum[r];
    }
  }
  __syncthreads();
  if (tid < 64) fq[tid] = gamma[0] / (red[tid * 2] + red[tid * 2 + 1]);
  __syncthreads();

  // ---- epilogue: 4 chunks of 128 channels; repack via LDS -> coalesced f32x4
  float* rep = (float*)smem;
  const size_t obase = (size_t)bn * CCH * PP + qt0;
#pragma unroll
  for (int chunk = 0; chunk < 4; ++chunk) {
    if ((w >> 1) == chunk) {
#pragma unroll
      for (int i = 0; i < 4; ++i)
#pragma unroll
        for (int j = 0; j < 4; ++j) {
          const int q = (j << 4) + (l & 15);
          const float f = fq[q];
          const int c0 = ((w & 1) << 6) + (i << 4) + ((l >> 4) << 2);
#pragma unroll
          for (int r = 0; r < 4; ++r) rep[(c0 + r) * 68 + q] = acc[i][j][r] * f;
        }
    }
    __syncthreads();
#pragma unroll
    for (int it = 0; it < 4; ++it) {
      const int cp = it * 512 + tid, cl = cp >> 4, q4 = cp & 15;
      const size_t gi = obase + (size_t)(chunk * 128 + cl) * PP + q4 * 4;
      const f32x4 tv = *(const f32x4*)&tensor[gi];
      const f32x4 rv = *(const f32x4*)&rep[cl * 68 + q4 * 4];
      *(f32x4*)&out[gi] = tv + rv;
    }
    __syncthreads();
  }
}

// -------------------------------------------------------------------- launcher
extern "C" void kernel_launch(void* const* d_in, const int* in_sizes, int n_in,
                              void* d_out, int out_size, void* d_ws, size_t ws_size,
                              hipStream_t stream) {
  const float* tensor  = (const float*)d_in[0];
  const float* key_w   = (const float*)d_in[1];
  const float* key_b   = (const float*)d_in[2];
  const float* query_w = (const float*)d_in[3];
  const float* query_b = (const float*)d_in[4];
  const float* value_w = (const float*)d_in[5];
  const float* value_b = (const float*)d_in[6];
  const float* gamma   = (const float*)d_in[7];

  char* ws = (char*)d_ws;
  size_t off = 0;
  auto alloc = [&](size_t bytes) -> char* {
    char* p = ws + off;
    off += (bytes + 255) & ~(size_t)255;
    return p;
  };
  bf16* xt_hi  = (bf16*)alloc((size_t)NBATCH * PP * CCH * 2);
  bf16* xt_lo  = (bf16*)alloc((size_t)NBATCH * PP * CCH * 2);
  bf16* wqk_hi = (bf16*)alloc(128 * 512 * 2);
  bf16* wqk_lo = (bf16*)alloc(128 * 512 * 2);
  bf16* wv     = (bf16*)alloc(512 * 512 * 2);
  float* bias_qk = (float*)alloc(128 * 4);
  float* bias_v  = (float*)alloc(512 * 4);
  bf16* q_hi = (bf16*)alloc((size_t)NBATCH * PP * OCH * 2);
  bf16* q_lo = (bf16*)alloc((size_t)NBATCH * PP * OCH * 2);
  bf16* k_hi = (bf16*)alloc((size_t)NBATCH * PP * OCH * 2);
  bf16* k_lo = (bf16*)alloc((size_t)NBATCH * PP * OCH * 2);
  bf16* vbuf = (bf16*)alloc((size_t)NBATCH * CCH * PP * 2);
  (void)ws_size; (void)in_sizes; (void)n_in; (void)out_size;

  prep_transpose_kernel<<<dim3(3331), dim3(256), 0, stream>>>(
      tensor, key_w, key_b, query_w, query_b, value_w, value_b,
      xt_hi, xt_lo, wqk_hi, wqk_lo, wv, bias_qk, bias_v);

  gemm_qkv_kernel<<<dim3(640), dim3(256), 0, stream>>>(
      wqk_hi, wqk_lo, wv, xt_hi, xt_lo, bias_qk, bias_v,
      q_hi, q_lo, k_hi, k_lo, vbuf);

  fused_attn_kernel<<<dim3(256), dim3(512), 0, stream>>>(
      q_hi, q_lo, k_hi, k_lo, vbuf, tensor, gamma, (float*)d_out);
}

// Round 13
// 96.388 us; speedup vs baseline: 1.5890x; 1.5890x over previous
//
#include <hip/hip_runtime.h>
#include <hip/hip_bf16.h>

typedef __hip_bfloat16 bf16;
typedef __attribute__((ext_vector_type(8))) short bf16x8;
typedef __attribute__((ext_vector_type(4))) float f32x4;

#define NBATCH 16
#define CCH    512
#define PP     1024
#define OCH    64

__device__ __forceinline__ void gload16(const void* g, void* l) {
  __builtin_amdgcn_global_load_lds(
      (const __attribute__((address_space(1))) void*)g,
      (__attribute__((address_space(3))) void*)l, 16, 0, 0);
}
__device__ __forceinline__ float bf2f(bf16 v) { return __bfloat162float(v); }
__device__ __forceinline__ bf16  f2bf(float v) { return __float2bfloat16(v); }

__device__ __forceinline__ void barrier_vm0() {
  asm volatile("s_waitcnt vmcnt(0)" ::: "memory");
  __builtin_amdgcn_s_barrier();
  asm volatile("" ::: "memory");
}
__device__ __forceinline__ void barrier_lgkm0() {
  asm volatile("s_waitcnt lgkmcnt(0)" ::: "memory");
  __builtin_amdgcn_s_barrier();
  asm volatile("" ::: "memory");
}

// --------------------------------------- merged prep (weights) + transpose/split
// blocks [0,2048): transpose+split 64x64 tiles; blocks [2048,3331): weight prep.
__global__ __launch_bounds__(256) void prep_transpose_kernel(
    const float* __restrict__ x,
    const float* __restrict__ key_w, const float* __restrict__ key_b,
    const float* __restrict__ query_w, const float* __restrict__ query_b,
    const float* __restrict__ value_w, const float* __restrict__ value_b,
    bf16* __restrict__ xhi, bf16* __restrict__ xlo,
    bf16* __restrict__ wqk_hi, bf16* __restrict__ wqk_lo,
    bf16* __restrict__ wv, float* __restrict__ bias_qk, float* __restrict__ bias_v) {
  __shared__ float tile[64 * 65];
  const int bid = blockIdx.x;
  const int tid = threadIdx.x;
  if (bid < 2048) {
    const int pt = bid & 15, ct = (bid >> 4) & 7, n = bid >> 7;
    const size_t xbase = ((size_t)n * CCH + ct * 64) * PP + pt * 64;
#pragma unroll
    for (int i = 0; i < 4; ++i) {
      const int chunk = i * 256 + tid;
      const int row = chunk >> 4, c4 = chunk & 15;
      const f32x4 v = *(const f32x4*)&x[xbase + (size_t)row * PP + c4 * 4];
#pragma unroll
      for (int m = 0; m < 4; ++m) tile[row * 65 + c4 * 4 + m] = v[m];
    }
    __syncthreads();
    const size_t obase = ((size_t)n * PP + pt * 64) * CCH + ct * 64;
#pragma unroll
    for (int ii = 0; ii < 2; ++ii) {
      const int p = ii * 32 + (tid >> 3);
      const int cu = tid & 7;
      bf16x8 hv, lv;
#pragma unroll
      for (int j = 0; j < 8; ++j) {
        const float f = tile[(cu * 8 + j) * 65 + p];
        const bf16 h = f2bf(f);
        const bf16 lo_ = f2bf(f - bf2f(h));
        short hs, ls;
        __builtin_memcpy(&hs, &h, 2);
        __builtin_memcpy(&ls, &lo_, 2);
        hv[j] = hs;
        lv[j] = ls;
      }
      const size_t oidx = obase + (size_t)p * CCH + cu * 8;
      *(bf16x8*)&xhi[oidx] = hv;
      *(bf16x8*)&xlo[oidx] = lv;
    }
  } else {
    const int t = (bid - 2048) * 256 + tid;
    const int TOT_QK = 128 * 512;
    const int TOT_V  = 512 * 512;
    if (t < TOT_QK) {
      const int m = t >> 9, c = t & 511;
      const float v = (m < 64) ? query_w[m * 512 + c] : key_w[(m - 64) * 512 + c];
      const bf16 hi = f2bf(v);
      wqk_hi[t] = hi;
      wqk_lo[t] = f2bf(v - bf2f(hi));
    } else if (t < TOT_QK + TOT_V) {
      const int u = t - TOT_QK;
      wv[u] = f2bf(value_w[u]);
    } else if (t < TOT_QK + TOT_V + 128) {
      const int m = t - (TOT_QK + TOT_V);
      bias_qk[m] = (m < 64) ? query_b[m] : key_b[m - 64];
    } else if (t < TOT_QK + TOT_V + 128 + 512) {
      const int m = t - (TOT_QK + TOT_V + 128);
      bias_v[m] = value_b[m];
    }
  }
}

// ------------------------------------- merged Q/K projection + V projection GEMM
// blocks [0,128): qk path (3-term hi/lo, M=128). blocks [128,640): v path
// (plain bf16, M=512). Concurrent residency fills CUs that qk alone left idle.
__global__ __launch_bounds__(256) void gemm_qkv_kernel(
    const bf16* __restrict__ Whi, const bf16* __restrict__ Wlo,
    const bf16* __restrict__ Wv,
    const bf16* __restrict__ XThi, const bf16* __restrict__ XTlo,
    const float* __restrict__ biasqk, const float* __restrict__ biasv,
    bf16* __restrict__ qhi, bf16* __restrict__ qlo,
    bf16* __restrict__ khi, bf16* __restrict__ klo,
    bf16* __restrict__ Vout) {
  __shared__ __align__(16) bf16 sm[4 * 128 * 64];  // 64KB union
  const int tid = threadIdx.x, l = tid & 63, w = tid >> 6;
  const int lrow = l >> 3, lcol = (l & 7) * 8, wr = w >> 1, wc = w & 1;
  const f32x4 z = {0.f, 0.f, 0.f, 0.f};
  f32x4 acc[4][4];
#pragma unroll
  for (int i = 0; i < 4; ++i)
#pragma unroll
    for (int j = 0; j < 4; ++j) acc[i][j] = z;

  if (blockIdx.x < 128) {
    // ---------------- qk path
    const int id = blockIdx.x;
    const int n0 = (id & 7) * 128, bn = id >> 3;
    const size_t xoff = (size_t)bn * PP * CCH;
    bf16* Ash = sm;
    bf16* Asl = sm + 8192;
    bf16* Bsh = sm + 16384;
    bf16* Bsl = sm + 24576;
    for (int kt = 0; kt < CCH; kt += 64) {
#pragma unroll
      for (int it = 0; it < 4; ++it) {
        const int chunk = w * 4 + it;
        const int ar = chunk * 8 + lrow;
        const int br = n0 + chunk * 8 + lrow;
        gload16(Whi + (size_t)ar * CCH + kt + lcol, &Ash[chunk * 512]);
        gload16(Wlo + (size_t)ar * CCH + kt + lcol, &Asl[chunk * 512]);
        gload16(XThi + xoff + (size_t)br * CCH + kt + lcol, &Bsh[chunk * 512]);
        gload16(XTlo + xoff + (size_t)br * CCH + kt + lcol, &Bsl[chunk * 512]);
      }
      __syncthreads();
#pragma unroll
      for (int kk = 0; kk < 2; ++kk) {
        bf16x8 ah[4], al[4], bh[4], bl[4];
        const int ko = kk * 32 + (l >> 4) * 8;
#pragma unroll
        for (int i = 0; i < 4; ++i) {
          const int r = (wr * 64 + i * 16 + (l & 15)) * 64 + ko;
          ah[i] = *(const bf16x8*)&Ash[r];
          al[i] = *(const bf16x8*)&Asl[r];
        }
#pragma unroll
        for (int j = 0; j < 4; ++j) {
          const int r = (wc * 64 + j * 16 + (l & 15)) * 64 + ko;
          bh[j] = *(const bf16x8*)&Bsh[r];
          bl[j] = *(const bf16x8*)&Bsl[r];
        }
#pragma unroll
        for (int i = 0; i < 4; ++i)
#pragma unroll
          for (int j = 0; j < 4; ++j) {
            acc[i][j] = __builtin_amdgcn_mfma_f32_16x16x32_bf16(ah[i], bh[j], acc[i][j], 0, 0, 0);
            acc[i][j] = __builtin_amdgcn_mfma_f32_16x16x32_bf16(ah[i], bl[j], acc[i][j], 0, 0, 0);
            acc[i][j] = __builtin_amdgcn_mfma_f32_16x16x32_bf16(al[i], bh[j], acc[i][j], 0, 0, 0);
          }
      }
      __syncthreads();
    }
    const size_t qoff = (size_t)bn * PP * OCH;
#pragma unroll
    for (int i = 0; i < 4; ++i)
#pragma unroll
      for (int j = 0; j < 4; ++j)
#pragma unroll
        for (int r = 0; r < 4; ++r) {
          const int m = wr * 64 + i * 16 + (l >> 4) * 4 + r;
          const int p = n0 + wc * 64 + j * 16 + (l & 15);
          const float v = acc[i][j][r] + biasqk[m];
          const bf16 hi = f2bf(v);
          const bf16 lo = f2bf(v - bf2f(hi));
          if (m < 64) {
            qhi[qoff + (size_t)p * OCH + m] = hi;
            qlo[qoff + (size_t)p * OCH + m] = lo;
          } else {
            khi[qoff + (size_t)p * OCH + (m - 64)] = hi;
            klo[qoff + (size_t)p * OCH + (m - 64)] = lo;
          }
        }
  } else {
    // ---------------- v path
    const int id = blockIdx.x - 128;
    const int n0 = (id & 7) * 128, m0 = ((id >> 3) & 3) * 128, bn = id >> 5;
    const size_t xoff = (size_t)bn * PP * CCH;
    bf16* As = sm;
    bf16* Bs = sm + 8192;
    for (int kt = 0; kt < CCH; kt += 64) {
#pragma unroll
      for (int it = 0; it < 4; ++it) {
        const int chunk = w * 4 + it;
        gload16(Wv + (size_t)(m0 + chunk * 8 + lrow) * CCH + kt + lcol, &As[chunk * 512]);
        gload16(XThi + xoff + (size_t)(n0 + chunk * 8 + lrow) * CCH + kt + lcol, &Bs[chunk * 512]);
      }
      __syncthreads();
#pragma unroll
      for (int kk = 0; kk < 2; ++kk) {
        bf16x8 a[4], b[4];
        const int ko = kk * 32 + (l >> 4) * 8;
#pragma unroll
        for (int i = 0; i < 4; ++i) a[i] = *(const bf16x8*)&As[(wr * 64 + i * 16 + (l & 15)) * 64 + ko];
#pragma unroll
        for (int j = 0; j < 4; ++j) b[j] = *(const bf16x8*)&Bs[(wc * 64 + j * 16 + (l & 15)) * 64 + ko];
#pragma unroll
        for (int i = 0; i < 4; ++i)
#pragma unroll
          for (int j = 0; j < 4; ++j)
            acc[i][j] = __builtin_amdgcn_mfma_f32_16x16x32_bf16(a[i], b[j], acc[i][j], 0, 0, 0);
      }
      __syncthreads();
    }
#pragma unroll
    for (int i = 0; i < 4; ++i)
#pragma unroll
      for (int j = 0; j < 4; ++j)
#pragma unroll
        for (int r = 0; r < 4; ++r) {
          const int m = m0 + wr * 64 + i * 16 + (l >> 4) * 4 + r;
          const int p = n0 + wc * 64 + j * 16 + (l & 15);
          Vout[(size_t)bn * CCH * PP + (size_t)m * PP + p] = f2bf(acc[i][j][r] + biasv[m]);
        }
  }
}

// ---------------------------------------------------- fused flash attention + epilogue
// R7 structure FROZEN (best measured): KT=32 dbuf K hi/lo + V in LDS via
// gload16 (swizzled source); P single-buffer; 2 barriers/tile; setprio around
// MFMA clusters. Only delta vs R7: epilogue half-0 tensor loads issued early
// (hidden under psum reduce + repack).
#define KT 32
#define NT 32

__global__ __launch_bounds__(512, 2) void fused_attn_kernel(
    const bf16* __restrict__ qhi, const bf16* __restrict__ qlo,
    const bf16* __restrict__ khi, const bf16* __restrict__ klo,
    const bf16* __restrict__ vbuf, const float* __restrict__ tensor,
    const float* __restrict__ gamma, float* __restrict__ out) {
  // byte offsets: Qh 0, Ql 8192, Kh{0,1} 16384/20480, Kl{0,1} 24576/28672,
  // V0 32768, V1 65536, P 98304 (4096). epilogue rep[256][68] f32 aliases base.
  __shared__ __align__(16) char smem[102400];
  __shared__ float red[128];
  __shared__ float fq[64];
  const int tid = threadIdx.x, l = tid & 63, w = tid >> 6;

  // XCD-grouped decode: XCD x gets batches {2x, 2x+1}
  const int d = blockIdx.x;
  const int idx = d >> 3;
  const int bn = (d & 7) * 2 + (idx >> 4);
  const int qt0 = (idx & 15) * 64;

  const size_t qkoff = (size_t)bn * PP * OCH;
  const size_t voff  = (size_t)bn * CCH * PP;
  char* Qh = smem;
  char* Ql = smem + 8192;
  char* Pb = smem + 98304;

  // ---- stage Q (hi/lo), once
  {
    const int s = (w << 6) | l;
    const int row = s >> 3, pu = s & 7, lu = pu ^ (row & 7);
    const size_t src = qkoff + (size_t)(qt0 + row) * OCH + lu * 8;
    gload16(qhi + src, Qh + w * 1024);
    gload16(qlo + src, Ql + w * 1024);
  }
  barrier_vm0();

  // ---- hoist Q fragments (loop-invariant)
  bf16x8 ah[2], al[2];
  {
    const int qrow = ((w & 3) << 4) + (l & 15);
#pragma unroll
    for (int h = 0; h < 2; ++h) {
      const int lu = (l >> 4) + 4 * h, pu = lu ^ (qrow & 7);
      ah[h] = *(const bf16x8*)(Qh + qrow * 128 + pu * 16);
      al[h] = *(const bf16x8*)(Ql + qrow * 128 + pu * 16);
    }
  }

  auto stage_kv = [&](int t, char* khD, char* klD, char* vD) {
    {
      const int s = ((w & 3) << 6) | l;
      const int row = s >> 3, pu = s & 7, lu = pu ^ (row & 7);
      const bf16* srcp = ((w < 4) ? khi : klo) + qkoff + (size_t)(t * KT + row) * OCH + lu * 8;
      gload16(srcp, ((w < 4) ? khD : klD) + (w & 3) * 1024);
    }
#pragma unroll
    for (int c4 = 0; c4 < 4; ++c4) {
      const int s = (w << 8) + (c4 << 6) + l;
      const int row = s >> 2, pu = s & 3, lu = pu ^ ((row >> 1) & 3);
      const bf16* srcp = vbuf + voff + (size_t)row * PP + t * KT + lu * 8;
      gload16(srcp, vD + ((w << 8) + (c4 << 6)) * 16);
    }
  };

  stage_kv(0, smem + 16384, smem + 24576, smem + 32768);

  f32x4 acc[4][4];
  const f32x4 z = {0.f, 0.f, 0.f, 0.f};
#pragma unroll
  for (int i = 0; i < 4; ++i)
#pragma unroll
    for (int j = 0; j < 4; ++j) acc[i][j] = z;
  float psum[4] = {0.f, 0.f, 0.f, 0.f};
  const int kf = w >> 2;

  for (int t = 0; t < NT; ++t) {
    char* khB = smem + 16384 + ((t & 1) ? 4096 : 0);
    char* klB = smem + 24576 + ((t & 1) ? 4096 : 0);
    char* vB  = smem + 32768 + ((t & 1) ? 32768 : 0);

    barrier_vm0();  // stage(t) resident everywhere; prev tile's compute done

    if (t + 1 < NT) {
      stage_kv(t + 1,
               smem + 16384 + ((t & 1) ? 0 : 4096),
               smem + 24576 + ((t & 1) ? 0 : 4096),
               smem + 32768 + ((t & 1) ? 0 : 32768));
    }

    // ---- S = Q.K^T for this wave's (qf = w&3, kf) 16x16 fragment
    bf16x8 kh_[2], kl_[2];
    const int krow = (kf << 4) + (l & 15);
#pragma unroll
    for (int h = 0; h < 2; ++h) {
      const int lu = (l >> 4) + 4 * h, pu = lu ^ (krow & 7);
      kh_[h] = *(const bf16x8*)(khB + krow * 128 + pu * 16);
      kl_[h] = *(const bf16x8*)(klB + krow * 128 + pu * 16);
    }
    __builtin_amdgcn_s_setprio(1);
    f32x4 s = z;
    s = __builtin_amdgcn_mfma_f32_16x16x32_bf16(ah[0], kh_[0], s, 0, 0, 0);
    s = __builtin_amdgcn_mfma_f32_16x16x32_bf16(ah[1], kh_[1], s, 0, 0, 0);
    s = __builtin_amdgcn_mfma_f32_16x16x32_bf16(al[0], kh_[0], s, 0, 0, 0);
    s = __builtin_amdgcn_mfma_f32_16x16x32_bf16(al[1], kh_[1], s, 0, 0, 0);
    s = __builtin_amdgcn_mfma_f32_16x16x32_bf16(ah[0], kl_[0], s, 0, 0, 0);
    s = __builtin_amdgcn_mfma_f32_16x16x32_bf16(ah[1], kl_[1], s, 0, 0, 0);
    __builtin_amdgcn_s_setprio(0);

    // ---- P = exp(s - 30) -> bf16, write to P_lds (swizzled), track row sums
#pragma unroll
    for (int r = 0; r < 4; ++r) {
      const float pv = __expf(s[r] - 30.f);
      const bf16 pb16 = f2bf(pv);
      psum[r] += bf2f(pb16);
      const int q = ((w & 3) << 4) + ((l >> 4) << 2) + r;
      const int k = (kf << 4) + (l & 15);
      const int pu = (k >> 3) ^ ((q >> 1) & 3);
      *(bf16*)(Pb + q * 64 + pu * 16 + (k & 7) * 2) = pb16;
    }
    barrier_lgkm0();  // P visible to all waves

    // ---- PV: acc[c-frag i][q-frag j] += V * P^T
    bf16x8 va[4], pb[4];
#pragma unroll
    for (int i = 0; i < 4; ++i) {
      const int crow = (w << 6) + (i << 4) + (l & 15);
      const int pu = (l >> 4) ^ ((crow >> 1) & 3);
      va[i] = *(const bf16x8*)(vB + crow * 64 + pu * 16);
    }
#pragma unroll
    for (int j = 0; j < 4; ++j) {
      const int prow = (j << 4) + (l & 15);
      const int pu = (l >> 4) ^ ((prow >> 1) & 3);
      pb[j] = *(const bf16x8*)(Pb + prow * 64 + pu * 16);
    }
    __builtin_amdgcn_s_setprio(1);
#pragma unroll
    for (int i = 0; i < 4; ++i)
#pragma unroll
      for (int j = 0; j < 4; ++j)
        acc[i][j] = __builtin_amdgcn_mfma_f32_16x16x32_bf16(va[i], pb[j], acc[i][j], 0, 0, 0);
    __builtin_amdgcn_s_setprio(0);
  }

  // ---- early-issue half-0 tensor loads (hidden under reduce + repack)
  f32x4 tv0[8];
#pragma unroll
  for (int it = 0; it < 8; ++it) {
    const int chunk = it * 512 + tid;
    const int cl = chunk >> 4, ch = chunk & 15;
    tv0[it] = *(const f32x4*)&tensor[((size_t)bn * CCH + cl) * PP + qt0 + ch * 4];
  }

  // ---- lsum: reduce psum over the 16 lanes sharing a q-row, combine kf halves
#pragma unroll
  for (int off = 1; off < 16; off <<= 1)
#pragma unroll
    for (int r = 0; r < 4; ++r) psum[r] += __shfl_xor(psum[r], off);
  if ((l & 15) == 0) {
#pragma unroll
    for (int r = 0; r < 4; ++r) {
      const int q = ((w & 3) << 4) + ((l >> 4) << 2) + r;
      red[q * 2 + kf] = psum[r];
    }
  }
  __syncthreads();
  if (tid < 64) fq[tid] = gamma[0] / (red[tid * 2] + red[tid * 2 + 1]);
  __syncthreads();

  // ---- epilogue: repack acc through LDS (rep[256 c][68]) -> coalesced float4
  float* rep = (float*)smem;  // stage buffers dead; red/fq are separate arrays
  for (int half = 0; half < 2; ++half) {
    if ((w >> 2) == half) {
#pragma unroll
      for (int i = 0; i < 4; ++i)
#pragma unroll
        for (int j = 0; j < 4; ++j) {
          const int q = (j << 4) + (l & 15);
          const float f = fq[q];
          const int c0 = ((w & 3) << 6) + (i << 4) + ((l >> 4) << 2);
#pragma unroll
          for (int r = 0; r < 4; ++r) rep[(c0 + r) * 68 + q] = acc[i][j][r] * f;
        }
    }
    __syncthreads();
#pragma unroll
    for (int it = 0; it < 8; ++it) {
      const int chunk = it * 512 + tid;
      const int cl = chunk >> 4, ch = chunk & 15;
      const size_t gi = ((size_t)bn * CCH + half * 256 + cl) * PP + qt0 + ch * 4;
      const f32x4 tv = (half == 0) ? tv0[it] : *(const f32x4*)&tensor[gi];
      const f32x4 rv = *(const f32x4*)&rep[cl * 68 + ch * 4];
      *(f32x4*)&out[gi] = tv + rv;
    }
    __syncthreads();
  }
}

// -------------------------------------------------------------------- launcher
extern "C" void kernel_launch(void* const* d_in, const int* in_sizes, int n_in,
                              void* d_out, int out_size, void* d_ws, size_t ws_size,
                              hipStream_t stream) {
  const float* tensor  = (const float*)d_in[0];
  const float* key_w   = (const float*)d_in[1];
  const float* key_b   = (const float*)d_in[2];
  const float* query_w = (const float*)d_in[3];
  const float* query_b = (const float*)d_in[4];
  const float* value_w = (const float*)d_in[5];
  const float* value_b = (const float*)d_in[6];
  const float* gamma   = (const float*)d_in[7];

  char* ws = (char*)d_ws;
  size_t off = 0;
  auto alloc = [&](size_t bytes) -> char* {
    char* p = ws + off;
    off += (bytes + 255) & ~(size_t)255;
    return p;
  };
  bf16* xt_hi  = (bf16*)alloc((size_t)NBATCH * PP * CCH * 2);
  bf16* xt_lo  = (bf16*)alloc((size_t)NBATCH * PP * CCH * 2);
  bf16* wqk_hi = (bf16*)alloc(128 * 512 * 2);
  bf16* wqk_lo = (bf16*)alloc(128 * 512 * 2);
  bf16* wv     = (bf16*)alloc(512 * 512 * 2);
  float* bias_qk = (float*)alloc(128 * 4);
  float* bias_v  = (float*)alloc(512 * 4);
  bf16* q_hi = (bf16*)alloc((size_t)NBATCH * PP * OCH * 2);
  bf16* q_lo = (bf16*)alloc((size_t)NBATCH * PP * OCH * 2);
  bf16* k_hi = (bf16*)alloc((size_t)NBATCH * PP * OCH * 2);
  bf16* k_lo = (bf16*)alloc((size_t)NBATCH * PP * OCH * 2);
  bf16* vbuf = (bf16*)alloc((size_t)NBATCH * CCH * PP * 2);
  (void)ws_size; (void)in_sizes; (void)n_in; (void)out_size;

  prep_transpose_kernel<<<dim3(3331), dim3(256), 0, stream>>>(
      tensor, key_w, key_b, query_w, query_b, value_w, value_b,
      xt_hi, xt_lo, wqk_hi, wqk_lo, wv, bias_qk, bias_v);

  gemm_qkv_kernel<<<dim3(640), dim3(256), 0, stream>>>(
      wqk_hi, wqk_lo, wv, xt_hi, xt_lo, bias_qk, bias_v,
      q_hi, q_lo, k_hi, k_lo, vbuf);

  fused_attn_kernel<<<dim3(256), dim3(512), 0, stream>>>(
      q_hi, q_lo, k_hi, k_lo, vbuf, tensor, gamma, (float*)d_out);
}

// Round 14
// 91.699 us; speedup vs baseline: 1.6703x; 1.0511x over previous
//
#include <hip/hip_runtime.h>
#include <hip/hip_bf16.h>

typedef __hip_bfloat16 bf16;
typedef __attribute__((ext_vector_type(8))) short bf16x8;
typedef __attribute__((ext_vector_type(4))) float f32x4;

#define NBATCH 16
#define CCH    512
#define PP     1024
#define OCH    64

__device__ __forceinline__ void gload16(const void* g, void* l) {
  __builtin_amdgcn_global_load_lds(
      (const __attribute__((address_space(1))) void*)g,
      (__attribute__((address_space(3))) void*)l, 16, 0, 0);
}
__device__ __forceinline__ float bf2f(bf16 v) { return __bfloat162float(v); }
__device__ __forceinline__ bf16  f2bf(float v) { return __float2bfloat16(v); }

__device__ __forceinline__ void barrier_vm0() {
  asm volatile("s_waitcnt vmcnt(0)" ::: "memory");
  __builtin_amdgcn_s_barrier();
  asm volatile("" ::: "memory");
}
__device__ __forceinline__ void barrier_lgkm0() {
  asm volatile("s_waitcnt lgkmcnt(0)" ::: "memory");
  __builtin_amdgcn_s_barrier();
  asm volatile("" ::: "memory");
}

// ---------------------------------------------------------- weight prep (small)
__global__ void prep_kernel(const float* __restrict__ key_w, const float* __restrict__ key_b,
                            const float* __restrict__ query_w, const float* __restrict__ query_b,
                            const float* __restrict__ value_w, const float* __restrict__ value_b,
                            bf16* __restrict__ wqk_hi, bf16* __restrict__ wqk_lo,
                            bf16* __restrict__ wv, float* __restrict__ bias_qk,
                            float* __restrict__ bias_v) {
  const int t = blockIdx.x * blockDim.x + threadIdx.x;
  const int TOT_QK = 128 * 512;
  const int TOT_V  = 512 * 512;
  if (t < TOT_QK) {
    const int m = t >> 9, c = t & 511;
    const float v = (m < 64) ? query_w[m * 512 + c] : key_w[(m - 64) * 512 + c];
    const bf16 hi = f2bf(v);
    wqk_hi[t] = hi;
    wqk_lo[t] = f2bf(v - bf2f(hi));
  } else if (t < TOT_QK + TOT_V) {
    const int u = t - TOT_QK;
    wv[u] = f2bf(value_w[u]);
  } else if (t < TOT_QK + TOT_V + 128) {
    const int m = t - (TOT_QK + TOT_V);
    bias_qk[m] = (m < 64) ? query_b[m] : key_b[m - 64];
  } else if (t < TOT_QK + TOT_V + 128 + 512) {
    const int m = t - (TOT_QK + TOT_V + 128);
    bias_v[m] = value_b[m];
  }
}

// ---------------- merged QKV projection GEMM with IN-KERNEL transpose of x ----
// B-operand built per K-step: x tile staged fp32 untransposed (gload16, linear),
// columns pulled to registers (2-way-conflict b32 reads), converted to bf16
// hi/lo, written as swizzled B tiles (pu = chunk ^ (row&7)); fragment reads use
// the matching swizzle. Eliminates the prep_transpose kernel + 67 MB round trip.
// blocks [0,128): qk path (3-term hi/lo). blocks [128,640): v path (bf16).
__global__ __launch_bounds__(256) void gemm_qkv_kernel(
    const bf16* __restrict__ Whi, const bf16* __restrict__ Wlo,
    const bf16* __restrict__ Wv, const float* __restrict__ x,
    const float* __restrict__ biasqk, const float* __restrict__ biasv,
    bf16* __restrict__ qhi, bf16* __restrict__ qlo,
    bf16* __restrict__ khi, bf16* __restrict__ klo,
    bf16* __restrict__ Vout) {
  // sm: A tiles [0,32K) (qk: hi 16K + lo 16K; v: hi 16K). union [32K,64K):
  // Xs fp32 [64][128] staged, then overwritten by Bsh(16K)+Bsl(16K).
  __shared__ __align__(16) char sm[65536];
  const int tid = threadIdx.x, l = tid & 63, w = tid >> 6;
  const int li = l & 15, g = l >> 4;
  const int lrow = l >> 3, lcol = (l & 7) * 8, wr = w >> 1, wc = w & 1;
  const int tp = tid >> 1;           // transpose role: p-column 0..127
  const int tch = (tid & 1) * 32;    // transpose role: c-half base
  const f32x4 z = {0.f, 0.f, 0.f, 0.f};
  f32x4 acc[4][4];
#pragma unroll
  for (int i = 0; i < 4; ++i)
#pragma unroll
    for (int j = 0; j < 4; ++j) acc[i][j] = z;

  char* Xs  = sm + 32768;
  char* Bsh = sm + 32768;
  char* Bsl = sm + 49152;

  if (blockIdx.x < 128) {
    // ---------------- qk path
    const int id = blockIdx.x;
    const int n0 = (id & 7) * 128, bn = id >> 3;
    const float* xb = x + (size_t)bn * CCH * PP;
    bf16* Ash = (bf16*)sm;
    bf16* Asl = (bf16*)(sm + 16384);

    for (int kt = 0; kt < CCH; kt += 64) {
      // stage W hi/lo (prepped bf16, linear) + x tile (fp32, untransposed)
#pragma unroll
      for (int it = 0; it < 4; ++it) {
        const int chunk = w * 4 + it;
        const int ar = chunk * 8 + lrow;
        gload16(Whi + (size_t)ar * CCH + kt + lcol, &Ash[chunk * 512]);
        gload16(Wlo + (size_t)ar * CCH + kt + lcol, &Asl[chunk * 512]);
      }
#pragma unroll
      for (int i = 0; i < 8; ++i) {
        const int s = i * 256 + w * 64 + l;        // chunk id 0..2047
        const int row = s >> 5, col16 = s & 31;    // row=c-local, col16=16B unit in p
        gload16(xb + (size_t)(kt + row) * PP + n0 + col16 * 4,
                Xs + (i * 256 + w * 64) * 16);
      }
      __syncthreads();

      // transpose-convert: column tp, c-range [tch, tch+32) -> registers
      float f[32];
#pragma unroll
      for (int k = 0; k < 32; ++k)
        f[k] = *(const float*)(Xs + (size_t)(tch + k) * 512 + tp * 4);
      barrier_lgkm0();  // all column reads done before Bs overwrites Xs
#pragma unroll
      for (int k2 = 0; k2 < 4; ++k2) {
        bf16x8 hv, lv;
#pragma unroll
        for (int j = 0; j < 8; ++j) {
          const float ff = f[k2 * 8 + j];
          const bf16 h = f2bf(ff);
          const bf16 lo_ = f2bf(ff - bf2f(h));
          short hs, ls;
          __builtin_memcpy(&hs, &h, 2);
          __builtin_memcpy(&ls, &lo_, 2);
          hv[j] = hs;
          lv[j] = ls;
        }
        const int chunk = (tch >> 3) + k2;
        const int pu = chunk ^ (tp & 7);
        *(bf16x8*)(Bsh + tp * 128 + pu * 16) = hv;
        *(bf16x8*)(Bsl + tp * 128 + pu * 16) = lv;
      }
      barrier_lgkm0();  // B tiles visible

#pragma unroll
      for (int kk = 0; kk < 2; ++kk) {
        bf16x8 ah[4], al[4], bh[4], bl[4];
        const int ko = kk * 32 + g * 8;
#pragma unroll
        for (int i = 0; i < 4; ++i) {
          const int r = (wr * 64 + i * 16 + li) * 64 + ko;
          ah[i] = *(const bf16x8*)&Ash[r];
          al[i] = *(const bf16x8*)&Asl[r];
        }
#pragma unroll
        for (int j = 0; j < 4; ++j) {
          const int row = wc * 64 + j * 16 + li;
          const int pu = (4 * kk + g) ^ (row & 7);
          bh[j] = *(const bf16x8*)(Bsh + row * 128 + pu * 16);
          bl[j] = *(const bf16x8*)(Bsl + row * 128 + pu * 16);
        }
#pragma unroll
        for (int i = 0; i < 4; ++i)
#pragma unroll
          for (int j = 0; j < 4; ++j) {
            acc[i][j] = __builtin_amdgcn_mfma_f32_16x16x32_bf16(ah[i], bh[j], acc[i][j], 0, 0, 0);
            acc[i][j] = __builtin_amdgcn_mfma_f32_16x16x32_bf16(ah[i], bl[j], acc[i][j], 0, 0, 0);
            acc[i][j] = __builtin_amdgcn_mfma_f32_16x16x32_bf16(al[i], bh[j], acc[i][j], 0, 0, 0);
          }
      }
      __syncthreads();  // fragment reads done before next-step staging overwrites
    }
    const size_t qoff = (size_t)bn * PP * OCH;
#pragma unroll
    for (int i = 0; i < 4; ++i)
#pragma unroll
      for (int j = 0; j < 4; ++j)
#pragma unroll
        for (int r = 0; r < 4; ++r) {
          const int m = wr * 64 + i * 16 + g * 4 + r;
          const int p = n0 + wc * 64 + j * 16 + li;
          const float v = acc[i][j][r] + biasqk[m];
          const bf16 hi = f2bf(v);
          const bf16 lo = f2bf(v - bf2f(hi));
          if (m < 64) {
            qhi[qoff + (size_t)p * OCH + m] = hi;
            qlo[qoff + (size_t)p * OCH + m] = lo;
          } else {
            khi[qoff + (size_t)p * OCH + (m - 64)] = hi;
            klo[qoff + (size_t)p * OCH + (m - 64)] = lo;
          }
        }
  } else {
    // ---------------- v path (hi-only B)
    const int id = blockIdx.x - 128;
    const int n0 = (id & 7) * 128, m0 = ((id >> 3) & 3) * 128, bn = id >> 5;
    const float* xb = x + (size_t)bn * CCH * PP;
    bf16* As = (bf16*)sm;

    for (int kt = 0; kt < CCH; kt += 64) {
#pragma unroll
      for (int it = 0; it < 4; ++it) {
        const int chunk = w * 4 + it;
        gload16(Wv + (size_t)(m0 + chunk * 8 + lrow) * CCH + kt + lcol, &As[chunk * 512]);
      }
#pragma unroll
      for (int i = 0; i < 8; ++i) {
        const int s = i * 256 + w * 64 + l;
        const int row = s >> 5, col16 = s & 31;
        gload16(xb + (size_t)(kt + row) * PP + n0 + col16 * 4,
                Xs + (i * 256 + w * 64) * 16);
      }
      __syncthreads();

      float f[32];
#pragma unroll
      for (int k = 0; k < 32; ++k)
        f[k] = *(const float*)(Xs + (size_t)(tch + k) * 512 + tp * 4);
      barrier_lgkm0();
#pragma unroll
      for (int k2 = 0; k2 < 4; ++k2) {
        bf16x8 hv;
#pragma unroll
        for (int j = 0; j < 8; ++j) {
          const bf16 h = f2bf(f[k2 * 8 + j]);
          short hs;
          __builtin_memcpy(&hs, &h, 2);
          hv[j] = hs;
        }
        const int chunk = (tch >> 3) + k2;
        const int pu = chunk ^ (tp & 7);
        *(bf16x8*)(Bsh + tp * 128 + pu * 16) = hv;
      }
      barrier_lgkm0();

#pragma unroll
      for (int kk = 0; kk < 2; ++kk) {
        bf16x8 a[4], b[4];
        const int ko = kk * 32 + g * 8;
#pragma unroll
        for (int i = 0; i < 4; ++i) a[i] = *(const bf16x8*)&As[(wr * 64 + i * 16 + li) * 64 + ko];
#pragma unroll
        for (int j = 0; j < 4; ++j) {
          const int row = wc * 64 + j * 16 + li;
          const int pu = (4 * kk + g) ^ (row & 7);
          b[j] = *(const bf16x8*)(Bsh + row * 128 + pu * 16);
        }
#pragma unroll
        for (int i = 0; i < 4; ++i)
#pragma unroll
          for (int j = 0; j < 4; ++j)
            acc[i][j] = __builtin_amdgcn_mfma_f32_16x16x32_bf16(a[i], b[j], acc[i][j], 0, 0, 0);
      }
      __syncthreads();
    }
#pragma unroll
    for (int i = 0; i < 4; ++i)
#pragma unroll
      for (int j = 0; j < 4; ++j)
#pragma unroll
        for (int r = 0; r < 4; ++r) {
          const int m = m0 + wr * 64 + i * 16 + g * 4 + r;
          const int p = n0 + wc * 64 + j * 16 + li;
          Vout[(size_t)bn * CCH * PP + (size_t)m * PP + p] = f2bf(acc[i][j][r] + biasv[m]);
        }
  }
}

// ---------------------------------------------------- fused flash attention + epilogue
// R7/R13 structure FROZEN (best measured). Unchanged.
#define KT 32
#define NT 32

__global__ __launch_bounds__(512, 2) void fused_attn_kernel(
    const bf16* __restrict__ qhi, const bf16* __restrict__ qlo,
    const bf16* __restrict__ khi, const bf16* __restrict__ klo,
    const bf16* __restrict__ vbuf, const float* __restrict__ tensor,
    const float* __restrict__ gamma, float* __restrict__ out) {
  __shared__ __align__(16) char smem[102400];
  __shared__ float red[128];
  __shared__ float fq[64];
  const int tid = threadIdx.x, l = tid & 63, w = tid >> 6;

  const int d = blockIdx.x;
  const int idx = d >> 3;
  const int bn = (d & 7) * 2 + (idx >> 4);
  const int qt0 = (idx & 15) * 64;

  const size_t qkoff = (size_t)bn * PP * OCH;
  const size_t voff  = (size_t)bn * CCH * PP;
  char* Qh = smem;
  char* Ql = smem + 8192;
  char* Pb = smem + 98304;

  {
    const int s = (w << 6) | l;
    const int row = s >> 3, pu = s & 7, lu = pu ^ (row & 7);
    const size_t src = qkoff + (size_t)(qt0 + row) * OCH + lu * 8;
    gload16(qhi + src, Qh + w * 1024);
    gload16(qlo + src, Ql + w * 1024);
  }
  barrier_vm0();

  bf16x8 ah[2], al[2];
  {
    const int qrow = ((w & 3) << 4) + (l & 15);
#pragma unroll
    for (int h = 0; h < 2; ++h) {
      const int lu = (l >> 4) + 4 * h, pu = lu ^ (qrow & 7);
      ah[h] = *(const bf16x8*)(Qh + qrow * 128 + pu * 16);
      al[h] = *(const bf16x8*)(Ql + qrow * 128 + pu * 16);
    }
  }

  auto stage_kv = [&](int t, char* khD, char* klD, char* vD) {
    {
      const int s = ((w & 3) << 6) | l;
      const int row = s >> 3, pu = s & 7, lu = pu ^ (row & 7);
      const bf16* srcp = ((w < 4) ? khi : klo) + qkoff + (size_t)(t * KT + row) * OCH + lu * 8;
      gload16(srcp, ((w < 4) ? khD : klD) + (w & 3) * 1024);
    }
#pragma unroll
    for (int c4 = 0; c4 < 4; ++c4) {
      const int s = (w << 8) + (c4 << 6) + l;
      const int row = s >> 2, pu = s & 3, lu = pu ^ ((row >> 1) & 3);
      const bf16* srcp = vbuf + voff + (size_t)row * PP + t * KT + lu * 8;
      gload16(srcp, vD + ((w << 8) + (c4 << 6)) * 16);
    }
  };

  stage_kv(0, smem + 16384, smem + 24576, smem + 32768);

  f32x4 acc[4][4];
  const f32x4 z = {0.f, 0.f, 0.f, 0.f};
#pragma unroll
  for (int i = 0; i < 4; ++i)
#pragma unroll
    for (int j = 0; j < 4; ++j) acc[i][j] = z;
  float psum[4] = {0.f, 0.f, 0.f, 0.f};
  const int kf = w >> 2;

  for (int t = 0; t < NT; ++t) {
    char* khB = smem + 16384 + ((t & 1) ? 4096 : 0);
    char* klB = smem + 24576 + ((t & 1) ? 4096 : 0);
    char* vB  = smem + 32768 + ((t & 1) ? 32768 : 0);

    barrier_vm0();

    if (t + 1 < NT) {
      stage_kv(t + 1,
               smem + 16384 + ((t & 1) ? 0 : 4096),
               smem + 24576 + ((t & 1) ? 0 : 4096),
               smem + 32768 + ((t & 1) ? 0 : 32768));
    }

    bf16x8 kh_[2], kl_[2];
    const int krow = (kf << 4) + (l & 15);
#pragma unroll
    for (int h = 0; h < 2; ++h) {
      const int lu = (l >> 4) + 4 * h, pu = lu ^ (krow & 7);
      kh_[h] = *(const bf16x8*)(khB + krow * 128 + pu * 16);
      kl_[h] = *(const bf16x8*)(klB + krow * 128 + pu * 16);
    }
    __builtin_amdgcn_s_setprio(1);
    f32x4 s = z;
    s = __builtin_amdgcn_mfma_f32_16x16x32_bf16(ah[0], kh_[0], s, 0, 0, 0);
    s = __builtin_amdgcn_mfma_f32_16x16x32_bf16(ah[1], kh_[1], s, 0, 0, 0);
    s = __builtin_amdgcn_mfma_f32_16x16x32_bf16(al[0], kh_[0], s, 0, 0, 0);
    s = __builtin_amdgcn_mfma_f32_16x16x32_bf16(al[1], kh_[1], s, 0, 0, 0);
    s = __builtin_amdgcn_mfma_f32_16x16x32_bf16(ah[0], kl_[0], s, 0, 0, 0);
    s = __builtin_amdgcn_mfma_f32_16x16x32_bf16(ah[1], kl_[1], s, 0, 0, 0);
    __builtin_amdgcn_s_setprio(0);

#pragma unroll
    for (int r = 0; r < 4; ++r) {
      const float pv = __expf(s[r] - 30.f);
      const bf16 pb16 = f2bf(pv);
      psum[r] += bf2f(pb16);
      const int q = ((w & 3) << 4) + ((l >> 4) << 2) + r;
      const int k = (kf << 4) + (l & 15);
      const int pu = (k >> 3) ^ ((q >> 1) & 3);
      *(bf16*)(Pb + q * 64 + pu * 16 + (k & 7) * 2) = pb16;
    }
    barrier_lgkm0();

    bf16x8 va[4], pb[4];
#pragma unroll
    for (int i = 0; i < 4; ++i) {
      const int crow = (w << 6) + (i << 4) + (l & 15);
      const int pu = (l >> 4) ^ ((crow >> 1) & 3);
      va[i] = *(const bf16x8*)(vB + crow * 64 + pu * 16);
    }
#pragma unroll
    for (int j = 0; j < 4; ++j) {
      const int prow = (j << 4) + (l & 15);
      const int pu = (l >> 4) ^ ((prow >> 1) & 3);
      pb[j] = *(const bf16x8*)(Pb + prow * 64 + pu * 16);
    }
    __builtin_amdgcn_s_setprio(1);
#pragma unroll
    for (int i = 0; i < 4; ++i)
#pragma unroll
      for (int j = 0; j < 4; ++j)
        acc[i][j] = __builtin_amdgcn_mfma_f32_16x16x32_bf16(va[i], pb[j], acc[i][j], 0, 0, 0);
    __builtin_amdgcn_s_setprio(0);
  }

  f32x4 tv0[8];
#pragma unroll
  for (int it = 0; it < 8; ++it) {
    const int chunk = it * 512 + tid;
    const int cl = chunk >> 4, ch = chunk & 15;
    tv0[it] = *(const f32x4*)&tensor[((size_t)bn * CCH + cl) * PP + qt0 + ch * 4];
  }

#pragma unroll
  for (int off = 1; off < 16; off <<= 1)
#pragma unroll
    for (int r = 0; r < 4; ++r) psum[r] += __shfl_xor(psum[r], off);
  if ((l & 15) == 0) {
#pragma unroll
    for (int r = 0; r < 4; ++r) {
      const int q = ((w & 3) << 4) + ((l >> 4) << 2) + r;
      red[q * 2 + kf] = psum[r];
    }
  }
  __syncthreads();
  if (tid < 64) fq[tid] = gamma[0] / (red[tid * 2] + red[tid * 2 + 1]);
  __syncthreads();

  float* rep = (float*)smem;
  for (int half = 0; half < 2; ++half) {
    if ((w >> 2) == half) {
#pragma unroll
      for (int i = 0; i < 4; ++i)
#pragma unroll
        for (int j = 0; j < 4; ++j) {
          const int q = (j << 4) + (l & 15);
          const float f = fq[q];
          const int c0 = ((w & 3) << 6) + (i << 4) + ((l >> 4) << 2);
#pragma unroll
          for (int r = 0; r < 4; ++r) rep[(c0 + r) * 68 + q] = acc[i][j][r] * f;
        }
    }
    __syncthreads();
#pragma unroll
    for (int it = 0; it < 8; ++it) {
      const int chunk = it * 512 + tid;
      const int cl = chunk >> 4, ch = chunk & 15;
      const size_t gi = ((size_t)bn * CCH + half * 256 + cl) * PP + qt0 + ch * 4;
      const f32x4 tv = (half == 0) ? tv0[it] : *(const f32x4*)&tensor[gi];
      const f32x4 rv = *(const f32x4*)&rep[cl * 68 + ch * 4];
      *(f32x4*)&out[gi] = tv + rv;
    }
    __syncthreads();
  }
}

// -------------------------------------------------------------------- launcher
extern "C" void kernel_launch(void* const* d_in, const int* in_sizes, int n_in,
                              void* d_out, int out_size, void* d_ws, size_t ws_size,
                              hipStream_t stream) {
  const float* tensor  = (const float*)d_in[0];
  const float* key_w   = (const float*)d_in[1];
  const float* key_b   = (const float*)d_in[2];
  const float* query_w = (const float*)d_in[3];
  const float* query_b = (const float*)d_in[4];
  const float* value_w = (const float*)d_in[5];
  const float* value_b = (const float*)d_in[6];
  const float* gamma   = (const float*)d_in[7];

  char* ws = (char*)d_ws;
  size_t off = 0;
  auto alloc = [&](size_t bytes) -> char* {
    char* p = ws + off;
    off += (bytes + 255) & ~(size_t)255;
    return p;
  };
  bf16* wqk_hi = (bf16*)alloc(128 * 512 * 2);
  bf16* wqk_lo = (bf16*)alloc(128 * 512 * 2);
  bf16* wv     = (bf16*)alloc(512 * 512 * 2);
  float* bias_qk = (float*)alloc(128 * 4);
  float* bias_v  = (float*)alloc(512 * 4);
  bf16* q_hi = (bf16*)alloc((size_t)NBATCH * PP * OCH * 2);
  bf16* q_lo = (bf16*)alloc((size_t)NBATCH * PP * OCH * 2);
  bf16* k_hi = (bf16*)alloc((size_t)NBATCH * PP * OCH * 2);
  bf16* k_lo = (bf16*)alloc((size_t)NBATCH * PP * OCH * 2);
  bf16* vbuf = (bf16*)alloc((size_t)NBATCH * CCH * PP * 2);
  (void)ws_size; (void)in_sizes; (void)n_in; (void)out_size;

  prep_kernel<<<dim3(1283), dim3(256), 0, stream>>>(
      key_w, key_b, query_w, query_b, value_w, value_b,
      wqk_hi, wqk_lo, wv, bias_qk, bias_v);

  gemm_qkv_kernel<<<dim3(640), dim3(256), 0, stream>>>(
      wqk_hi, wqk_lo, wv, tensor, bias_qk, bias_v,
      q_hi, q_lo, k_hi, k_lo, vbuf);

  fused_attn_kernel<<<dim3(256), dim3(512), 0, stream>>>(
      q_hi, q_lo, k_hi, k_lo, vbuf, tensor, gamma, (float*)d_out);
}